// Round 3
// baseline (49741.251 us; speedup 1.0000x reference)
//
#include <hip/hip_runtime.h>
#include <stdint.h>

typedef short short8 __attribute__((ext_vector_type(8)));
typedef float floatx4 __attribute__((ext_vector_type(4)));

#define LOG2E 1.44269504088896340736f

__device__ __forceinline__ float bf2f(unsigned short u) {
  unsigned v = ((unsigned)u) << 16;
  return __builtin_bit_cast(float, v);
}
__device__ __forceinline__ unsigned short f2bf(float f) {
  unsigned v = __builtin_bit_cast(unsigned, f);
  v += 0x7FFFu + ((v >> 16) & 1u);   // RNE
  return (unsigned short)(v >> 16);
}
__device__ __forceinline__ float fast_exp2(float x) {
#if __has_builtin(__builtin_amdgcn_exp2f)
  return __builtin_amdgcn_exp2f(x);
#else
  return exp2f(x);
#endif
}
__device__ __forceinline__ float fast_rcp(float x) {
#if __has_builtin(__builtin_amdgcn_rcpf)
  return __builtin_amdgcn_rcpf(x);
#else
  return 1.0f / x;
#endif
}
__device__ __forceinline__ float fsig(float x) {
  return fast_rcp(1.0f + fast_exp2(-LOG2E * x));
}
__device__ __forceinline__ float ftanh(float x) {
  float e = fast_exp2(2.0f * LOG2E * x);
  return 1.0f - 2.0f * fast_rcp(e + 1.0f);
}
__device__ __forceinline__ floatx4 mfma16(short8 a, short8 b, floatx4 c) {
  return __builtin_amdgcn_mfma_f32_16x16x32_bf16(a, b, c, 0, 0, 0);
}

// ---------------------------------------------------------------------------
// Dtype detection: if the buffer is float32, even-indexed u16 halves are float
// mantissa bits -> ~6% have bf16-exponent >= 0xF0. If bf16 (0.05-scaled
// weights), exponent <= 125 always -> 0 hits. flag: 1 = f32, 0 = bf16.
// ---------------------------------------------------------------------------
__global__ __launch_bounds__(256) void detect_kernel(
    const unsigned short* __restrict__ w, int n_u16, int* __restrict__ flag)
{
  __shared__ int cnt;
  if (threadIdx.x == 0) cnt = 0;
  __syncthreads();
  int local = 0;
  for (int i = threadIdx.x * 2; i < n_u16; i += 512) {  // even indices only
    unsigned e = (w[i] >> 7) & 0xFF;
    if (e >= 0xF0) local++;
  }
  atomicAdd(&cnt, local);
  __syncthreads();
  if (threadIdx.x == 0) *flag = (cnt > 64) ? 1 : 0;
}

// ---------------------------------------------------------------------------
// Canonicalize a tensor to bf16 in ws (copy if already bf16, downcast if f32).
// src_off is in ELEMENTS (applied after dtype branch).
// ---------------------------------------------------------------------------
__global__ __launch_bounds__(256) void convert_kernel(
    const void* __restrict__ src, size_t src_off,
    unsigned short* __restrict__ dst, int n, const int* __restrict__ flag)
{
  const int base = (int)(blockIdx.x * 256 + threadIdx.x) * 4;
  if (base >= n) return;
  if (*flag) {
    const float* s = (const float*)src + src_off;
#pragma unroll
    for (int j = 0; j < 4; ++j)
      if (base + j < n) dst[base + j] = f2bf(s[base + j]);
  } else {
    const unsigned short* s = (const unsigned short*)src + src_off;
#pragma unroll
    for (int j = 0; j < 4; ++j)
      if (base + j < n) dst[base + j] = s[base + j];
  }
}

// ---------------------------------------------------------------------------
// Recurrent kernel: one workgroup per direction, persistent over `steps`.
// Z layout: [steps][1024][64] fp32 (col = dir*512 + gate*128 + unit, batch fastest)
// Wave w owns units [16w,16w+16); n-tile g = gate g for those units -> each
// lane ends up holding i,f,g,o for one (batch,unit) pair: no shuffles needed.
// ---------------------------------------------------------------------------
__global__ __launch_bounds__(512) void rec_kernel(
    const float* __restrict__ Z,
    const unsigned short* __restrict__ whh_f,   // [512][128] bf16
    const unsigned short* __restrict__ whh_b,
    unsigned short* __restrict__ ys,            // [steps][64][256] bf16
    float* __restrict__ cstate,                 // [2][64][128] fp32
    unsigned short* __restrict__ hstate,        // [2][64][128] bf16
    int steps, int init)
{
  __shared__ __align__(16) unsigned short hbuf[2][64][136];
  const int d = blockIdx.x;
  const unsigned short* whh = d ? whh_b : whh_f;
  const int tid = threadIdx.x;
  const int w = tid >> 6, lane = tid & 63, q = lane >> 4, cc = lane & 15;
  const int u = w * 16 + cc;

  // Whh as MFMA B-fragments, resident in registers for the whole kernel.
  // B[k][n]: lane holds B[q*8 + j][n=cc] per 32-K slice; B[k][col] = Whh[col][k].
  short8 bfrag[4][4];
#pragma unroll
  for (int g = 0; g < 4; ++g)
#pragma unroll
    for (int k = 0; k < 4; ++k)
      bfrag[g][k] = *(const short8*)(whh + (size_t)(g * 128 + u) * 128 + k * 32 + q * 8);

  float creg[16];
  const int row = tid >> 3, c16 = (tid & 7) * 16;
  if (init) {
#pragma unroll
    for (int j = 0; j < 16; ++j) creg[j] = 0.f;
#pragma unroll
    for (int i = 0; i < 16; ++i) hbuf[0][row][c16 + i] = 0;
  } else {
#pragma unroll
    for (int m = 0; m < 4; ++m)
#pragma unroll
      for (int r = 0; r < 4; ++r)
        creg[m * 4 + r] = cstate[(size_t)(d * 64 + m * 16 + q * 4 + r) * 128 + u];
    const unsigned short* hs = hstate + (size_t)d * 8192 + row * 128 + c16;
    *(short8*)&hbuf[0][row][c16]     = *(const short8*)hs;
    *(short8*)&hbuf[0][row][c16 + 8] = *(const short8*)(hs + 8);
  }
  __syncthreads();

  const float* zd = Z + (size_t)d * 512 * 64;
  for (int t = 0; t < steps; ++t) {
    const int cur = t & 1, nxt = cur ^ 1;
    const float* zt = zd + (size_t)t * 65536;
    // accumulator init = x-part of z (already includes bias), C/D layout
    floatx4 acc[4][4];
#pragma unroll
    for (int m = 0; m < 4; ++m)
#pragma unroll
      for (int g = 0; g < 4; ++g)
        acc[m][g] = *(const floatx4*)(zt + (size_t)(g * 128 + u) * 64 + m * 16 + q * 4);
    // h @ Whh^T
#pragma unroll
    for (int m = 0; m < 4; ++m) {
      short8 af[4];
#pragma unroll
      for (int k = 0; k < 4; ++k)
        af[k] = *(const short8*)&hbuf[cur][m * 16 + cc][k * 32 + q * 8];
#pragma unroll
      for (int g = 0; g < 4; ++g)
#pragma unroll
        for (int k = 0; k < 4; ++k)
          acc[m][g] = mfma16(af[k], bfrag[g][k], acc[m][g]);
    }
    // LSTM pointwise: lane owns (b = m*16+q*4+r, unit u), all 4 gates local
#pragma unroll
    for (int m = 0; m < 4; ++m)
#pragma unroll
      for (int r = 0; r < 4; ++r) {
        float zi = acc[m][0][r], zf = acc[m][1][r];
        float zg = acc[m][2][r], zo = acc[m][3][r];
        float cn = fsig(zf) * creg[m * 4 + r] + fsig(zi) * ftanh(zg);
        creg[m * 4 + r] = cn;
        float h = fsig(zo) * ftanh(cn);
        hbuf[nxt][m * 16 + q * 4 + r][u] = f2bf(h);
      }
    __syncthreads();
    // coalesced ys store from the freshly written h buffer
    unsigned short* yd = ys + (size_t)(t * 64 + row) * 256 + d * 128 + c16;
    *(short8*)yd       = *(const short8*)&hbuf[nxt][row][c16];
    *(short8*)(yd + 8) = *(const short8*)&hbuf[nxt][row][c16 + 8];
  }
  // persist state for next chunk
#pragma unroll
  for (int m = 0; m < 4; ++m)
#pragma unroll
    for (int r = 0; r < 4; ++r)
      cstate[(size_t)(d * 64 + m * 16 + q * 4 + r) * 128 + u] = creg[m * 4 + r];
  const int fin = steps & 1;
  unsigned short* hs = hstate + (size_t)d * 8192 + row * 128 + c16;
  *(short8*)hs       = *(const short8*)&hbuf[fin][row][c16];
  *(short8*)(hs + 8) = *(const short8*)&hbuf[fin][row][c16 + 8];
}

// ---------------------------------------------------------------------------
// Input GEMM: Z[t][col][b] = sum_k A[t*64+b][k]*Wih[col][k] + bias[col]
// grid (C, 4): blockIdx.x = t within chunk, blockIdx.y = 256-col slice.
// ---------------------------------------------------------------------------
template <int K>
__global__ __launch_bounds__(256, 4) void gemm_kernel(
    const unsigned short* __restrict__ A,    // [C*64][K] bf16
    const unsigned short* __restrict__ Bf,   // [512][K]
    const unsigned short* __restrict__ Bb,
    const unsigned short* __restrict__ biasf,  // [512]
    const unsigned short* __restrict__ biasb,
    float* __restrict__ Z)                   // [C][1024][64]
{
  constexpr int RS = K + 8;
  __shared__ __align__(16) unsigned short As[64 * RS];
  const int t = blockIdx.x, ns = blockIdx.y;
  const int tid = threadIdx.x, w = tid >> 6, lane = tid & 63;
  const int q = lane >> 4, cc = lane & 15;
  const unsigned short* Arow = A + (size_t)t * 64 * K;
  constexpr int K8 = K / 8;
  for (int ci = tid; ci < 64 * K8; ci += 256) {
    int r_ = ci / K8, c8 = ci % K8;
    *(short8*)&As[r_ * RS + c8 * 8] = *(const short8*)&Arow[r_ * K + c8 * 8];
  }
  __syncthreads();
  const int colbase = ns * 256 + w * 64;
  const unsigned short* Bp    = (colbase < 512) ? Bf : Bb;
  const unsigned short* biasp = (colbase < 512) ? biasf : biasb;
  const int cb = (colbase < 512) ? colbase : colbase - 512;
  floatx4 acc[4][4];
#pragma unroll
  for (int m = 0; m < 4; ++m)
#pragma unroll
    for (int n = 0; n < 4; ++n)
#pragma unroll
      for (int r = 0; r < 4; ++r) acc[m][n][r] = 0.f;
#pragma unroll
  for (int ks = 0; ks < K / 32; ++ks) {
    short8 af[4], bfr[4];
#pragma unroll
    for (int m = 0; m < 4; ++m)
      af[m] = *(const short8*)&As[(m * 16 + cc) * RS + ks * 32 + q * 8];
#pragma unroll
    for (int n = 0; n < 4; ++n)
      bfr[n] = *(const short8*)&Bp[(size_t)(cb + n * 16 + cc) * K + ks * 32 + q * 8];
#pragma unroll
    for (int m = 0; m < 4; ++m)
#pragma unroll
      for (int n = 0; n < 4; ++n)
        acc[m][n] = mfma16(af[m], bfr[n], acc[m][n]);
  }
#pragma unroll
  for (int n = 0; n < 4; ++n) {
    const int col = colbase + n * 16 + cc;
    const float bv = bf2f(biasp[cb + n * 16 + cc]);
#pragma unroll
    for (int m = 0; m < 4; ++m) {
      floatx4 v = acc[m][n];
      v += bv;
      *(floatx4*)&Z[(size_t)(t * 1024 + col) * 64 + m * 16 + q * 4] = v;
    }
  }
}

// ---------------------------------------------------------------------------
// FC head: one wave per (t,b): sigmoid(dot(ys1[t,b,:], fc_w) + fc_b).
// Output dtype selected by flag (1 = f32, 0 = bf16); out_off in elements.
// ---------------------------------------------------------------------------
__global__ __launch_bounds__(256) void fc_kernel(
    const unsigned short* __restrict__ ys,   // [n][256] bf16
    const unsigned short* __restrict__ fcw,  // [256]
    const unsigned short* __restrict__ fcb,  // [1]
    void* __restrict__ out, size_t out_off, int n,
    const int* __restrict__ flag)
{
  const int gw = (int)((blockIdx.x * 256 + threadIdx.x) >> 6);
  const int lane = threadIdx.x & 63;
  if (gw >= n) return;
  const unsigned short* rp = ys + (size_t)gw * 256 + lane * 4;
  float s = 0.f;
#pragma unroll
  for (int i = 0; i < 4; ++i) s += bf2f(rp[i]) * bf2f(fcw[lane * 4 + i]);
#pragma unroll
  for (int m = 32; m >= 1; m >>= 1) s += __shfl_xor(s, m, 64);
  if (lane == 0) {
    const float v = fsig(s + bf2f(fcb[0]));
    if (*flag) ((float*)out)[out_off + gw] = v;
    else       ((unsigned short*)out)[out_off + gw] = f2bf(v);
  }
}

extern "C" void kernel_launch(void* const* d_in, const int* in_sizes, int n_in,
                              void* d_out, int out_size, void* d_ws, size_t ws_size,
                              hipStream_t stream)
{
  (void)in_sizes; (void)n_in; (void)out_size;
  const int S = 4096;

  // ---- workspace layout (bytes) ----
  // [0,256)            : dtype flag (int)
  // [256, +1250304)    : canonical bf16 weights (625152 u16, offsets below)
  // then: xbuf C*6144 u16, Z0/Z1 C*65536 f32 each, ys0/ys1 C*16384 u16 each,
  //       c0/c1 16384 f32 each, h0/h1 16384 u16 each.
  int* flag = (int*)d_ws;
  unsigned short* wbuf = (unsigned short*)((char*)d_ws + 256);
  static const int woff[14] = {0,      49152,  114688, 115200, 164352, 229888,
                               230400, 361472, 427008, 427520, 558592, 624128,
                               624640, 624896};
  static const int wlen[14] = {49152, 65536, 512, 49152, 65536, 512,
                               131072, 65536, 512, 131072, 65536, 512,
                               256, 1};
  const size_t wbuf_end = 256 + 1250304;  // bytes

  // Per-step bytes: xbuf 12288 + Z0 262144 + Z1 262144 + ys0 32768 + ys1 32768
  //               = 602112.  Fixed: wbuf_end + state 196608.
  int C = 1;
  for (int cand = 1024; cand >= 1; cand >>= 1) {
    size_t need = (size_t)cand * 602112 + wbuf_end + 196608;
    if (need <= ws_size) { C = cand; break; }
  }
  unsigned short* xbuf = (unsigned short*)((char*)d_ws + wbuf_end);
  float* Z0 = (float*)((char*)xbuf + (size_t)C * 12288);
  float* Z1 = Z0 + (size_t)C * 65536;
  unsigned short* ys0 = (unsigned short*)(Z1 + (size_t)C * 65536);
  unsigned short* ys1 = ys0 + (size_t)C * 16384;
  float* c0 = (float*)(ys1 + (size_t)C * 16384);
  float* c1 = c0 + 16384;
  unsigned short* h0 = (unsigned short*)(c1 + 16384);
  unsigned short* h1 = h0 + 16384;

  // canonical weight pointers
  const unsigned short* wih0f = wbuf + woff[0];
  const unsigned short* whh0f = wbuf + woff[1];
  const unsigned short* b0f   = wbuf + woff[2];
  const unsigned short* wih0b = wbuf + woff[3];
  const unsigned short* whh0b = wbuf + woff[4];
  const unsigned short* b0b   = wbuf + woff[5];
  const unsigned short* wih1f = wbuf + woff[6];
  const unsigned short* whh1f = wbuf + woff[7];
  const unsigned short* b1f   = wbuf + woff[8];
  const unsigned short* wih1b = wbuf + woff[9];
  const unsigned short* whh1b = wbuf + woff[10];
  const unsigned short* b1b   = wbuf + woff[11];
  const unsigned short* fcw   = wbuf + woff[12];
  const unsigned short* fcb   = wbuf + woff[13];

  // 1) detect input dtype from wih0f (49152 elements under either dtype)
  detect_kernel<<<1, 256, 0, stream>>>((const unsigned short*)d_in[1], 49152, flag);
  // 2) canonicalize all 14 weight tensors (inputs 1..14) to bf16 in ws
  for (int i = 0; i < 14; ++i) {
    const int n = wlen[i];
    convert_kernel<<<(n + 1023) / 1024, 256, 0, stream>>>(
        d_in[1 + i], 0, wbuf + woff[i], n, flag);
  }

  const int nc = S / C;
  for (int c = 0; c < nc; ++c) {
    const int init = (c == 0) ? 1 : 0;
    const int nx = C * 6144;  // x chunk elements
    convert_kernel<<<(nx + 1023) / 1024, 256, 0, stream>>>(
        d_in[0], (size_t)c * nx, xbuf, nx, flag);
    gemm_kernel<96><<<dim3(C, 4), 256, 0, stream>>>(
        xbuf, wih0f, wih0b, b0f, b0b, Z0);
    rec_kernel<<<2, 512, 0, stream>>>(Z0, whh0f, whh0b, ys0, c0, h0, C, init);
    gemm_kernel<256><<<dim3(C, 4), 256, 0, stream>>>(
        ys0, wih1f, wih1b, b1f, b1b, Z1);
    rec_kernel<<<2, 512, 0, stream>>>(Z1, whh1f, whh1b, ys1, c1, h1, C, init);
    fc_kernel<<<C * 16, 256, 0, stream>>>(ys1, fcw, fcb, d_out,
                                          (size_t)c * C * 64, C * 64, flag);
  }
}

// Round 4
// 10218.961 us; speedup vs baseline: 4.8675x; 4.8675x over previous
//
#include <hip/hip_runtime.h>
#include <stdint.h>

typedef short short8 __attribute__((ext_vector_type(8)));
typedef short short4v __attribute__((ext_vector_type(4)));
typedef float floatx4 __attribute__((ext_vector_type(4)));

#define LOG2E 1.44269504088896340736f

__device__ __forceinline__ float bf2f(unsigned short u) {
  unsigned v = ((unsigned)u) << 16;
  return __builtin_bit_cast(float, v);
}
__device__ __forceinline__ unsigned short f2bf(float f) {
  unsigned v = __builtin_bit_cast(unsigned, f);
  v += 0x7FFFu + ((v >> 16) & 1u);   // RNE
  return (unsigned short)(v >> 16);
}
__device__ __forceinline__ float fast_exp2(float x) {
#if __has_builtin(__builtin_amdgcn_exp2f)
  return __builtin_amdgcn_exp2f(x);
#else
  return exp2f(x);
#endif
}
__device__ __forceinline__ float fast_rcp(float x) {
#if __has_builtin(__builtin_amdgcn_rcpf)
  return __builtin_amdgcn_rcpf(x);
#else
  return 1.0f / x;
#endif
}
__device__ __forceinline__ float fsig(float x) {
  return fast_rcp(1.0f + fast_exp2(-LOG2E * x));
}
__device__ __forceinline__ float ftanh(float x) {
  float e = fast_exp2(2.0f * LOG2E * x);
  return 1.0f - 2.0f * fast_rcp(e + 1.0f);
}
__device__ __forceinline__ floatx4 mfma16(short8 a, short8 b, floatx4 c) {
  return __builtin_amdgcn_mfma_f32_16x16x32_bf16(a, b, c, 0, 0, 0);
}

// ---------------------------------------------------------------------------
// Dtype detection: if the buffer is float32, even-indexed u16 halves are float
// mantissa bits -> ~6% have bf16-exponent >= 0xF0. If bf16 (0.05-scaled
// weights), exponent <= 125 always -> 0 hits. flag: 1 = f32, 0 = bf16.
// ---------------------------------------------------------------------------
__global__ __launch_bounds__(256) void detect_kernel(
    const unsigned short* __restrict__ w, int n_u16, int* __restrict__ flag)
{
  __shared__ int cnt;
  if (threadIdx.x == 0) cnt = 0;
  __syncthreads();
  int local = 0;
  for (int i = threadIdx.x * 2; i < n_u16; i += 512) {  // even indices only
    unsigned e = (w[i] >> 7) & 0xFF;
    if (e >= 0xF0) local++;
  }
  atomicAdd(&cnt, local);
  __syncthreads();
  if (threadIdx.x == 0) *flag = (cnt > 64) ? 1 : 0;
}

__global__ __launch_bounds__(256) void convert_kernel(
    const void* __restrict__ src, size_t src_off,
    unsigned short* __restrict__ dst, int n, const int* __restrict__ flag)
{
  const int base = (int)(blockIdx.x * 256 + threadIdx.x) * 4;
  if (base >= n) return;
  if (*flag) {
    const float* s = (const float*)src + src_off;
#pragma unroll
    for (int j = 0; j < 4; ++j)
      if (base + j < n) dst[base + j] = f2bf(s[base + j]);
  } else {
    const unsigned short* s = (const unsigned short*)src + src_off;
#pragma unroll
    for (int j = 0; j < 4; ++j)
      if (base + j < n) dst[base + j] = s[base + j];
  }
}

// ---------------------------------------------------------------------------
// Fused recurrent kernel. Two layer contexts (a = layer L0 chunk c,
// b = layer L1 chunk c-1); blocks 0..7 -> ctx a, 8..15 -> ctx b.
// Within a context: block = dir*4 + batch-group (16 batch rows each).
// The 16-row recurrence of one (dir, batch-group) is fully independent.
// Per block: M=16, N=512 (4 gates x 128 units), K=128. Wave w owns units
// [16w,16w+16); each lane holds all 4 gates of one (batch,unit) pair.
// ---------------------------------------------------------------------------
__global__ __launch_bounds__(512, 2) void rec_kernel(
    const float* __restrict__ Za, const unsigned short* __restrict__ whhfa,
    const unsigned short* __restrict__ whhba,
    unsigned short* __restrict__ ysa, float* __restrict__ ca,
    unsigned short* __restrict__ ha, int inita,
    const float* __restrict__ Zb, const unsigned short* __restrict__ whhfb,
    const unsigned short* __restrict__ whhbb,
    unsigned short* __restrict__ ysb, float* __restrict__ cb,
    unsigned short* __restrict__ hb, int initb,
    int steps)
{
  __shared__ __align__(16) unsigned short hbuf[2][16][136];
  const int blk = blockIdx.x;
  const float* Z;
  const unsigned short* whhF;
  const unsigned short* whhB;
  unsigned short* ys;
  float* cst;
  unsigned short* hst;
  int init;
  if (blk < 8) {
    Z = Za; whhF = whhfa; whhB = whhba; ys = ysa; cst = ca; hst = ha; init = inita;
  } else {
    Z = Zb; whhF = whhfb; whhB = whhbb; ys = ysb; cst = cb; hst = hb; init = initb;
  }
  const int d = (blk >> 2) & 1, bg = blk & 3;
  const unsigned short* whh = d ? whhB : whhF;

  const int tid = threadIdx.x;
  const int w = tid >> 6, lane = tid & 63, q = lane >> 4, cc = lane & 15;
  const int u = w * 16 + cc;

  // Whh as MFMA B-fragments, register-resident (64 VGPRs).
  short8 bfrag[4][4];
#pragma unroll
  for (int g = 0; g < 4; ++g)
#pragma unroll
    for (int k = 0; k < 4; ++k)
      bfrag[g][k] = *(const short8*)(whh + (size_t)(g * 128 + u) * 128 + k * 32 + q * 8);

  float creg[4];
  const int row = tid >> 5;          // 0..15
  const int col4 = (tid & 31) * 4;   // 0..124
  if (init) {
#pragma unroll
    for (int r = 0; r < 4; ++r) creg[r] = 0.f;
    short4v zz = {0, 0, 0, 0};
    *(short4v*)&hbuf[0][row][col4] = zz;
  } else {
#pragma unroll
    for (int r = 0; r < 4; ++r)
      creg[r] = cst[(size_t)(d * 64 + bg * 16 + q * 4 + r) * 128 + u];
    *(short4v*)&hbuf[0][row][col4] =
        *(const short4v*)(hst + (size_t)(d * 64 + bg * 16 + row) * 128 + col4);
  }
  __syncthreads();

  const int zlane = (d * 512 + u) * 64 + bg * 16 + q * 4;
  for (int t = 0; t < steps; ++t) {
    const int cur = t & 1, nxt = cur ^ 1;
    const float* zt = Z + (size_t)t * 65536 + zlane;
    floatx4 acc[4];
#pragma unroll
    for (int g = 0; g < 4; ++g)
      acc[g] = *(const floatx4*)(zt + g * 8192);
    short8 af[4];
#pragma unroll
    for (int k = 0; k < 4; ++k)
      af[k] = *(const short8*)&hbuf[cur][cc][k * 32 + q * 8];
#pragma unroll
    for (int g = 0; g < 4; ++g)
#pragma unroll
      for (int k = 0; k < 4; ++k)
        acc[g] = mfma16(af[k], bfrag[g][k], acc[g]);
    // pointwise: lane owns (batch bg*16 + q*4+r, unit u), gates local
#pragma unroll
    for (int r = 0; r < 4; ++r) {
      float zi = acc[0][r], zf = acc[1][r], zg = acc[2][r], zo = acc[3][r];
      float cn = fsig(zf) * creg[r] + fsig(zi) * ftanh(zg);
      creg[r] = cn;
      hbuf[nxt][q * 4 + r][u] = f2bf(fsig(zo) * ftanh(cn));
    }
    __syncthreads();
    unsigned short* yd = ys + (size_t)(t * 64 + bg * 16 + row) * 256 + d * 128 + col4;
    *(short4v*)yd = *(const short4v*)&hbuf[nxt][row][col4];
  }
#pragma unroll
  for (int r = 0; r < 4; ++r)
    cst[(size_t)(d * 64 + bg * 16 + q * 4 + r) * 128 + u] = creg[r];
  const int fin = steps & 1;
  *(short4v*)(hst + (size_t)(d * 64 + bg * 16 + row) * 128 + col4) =
      *(const short4v*)&hbuf[fin][row][col4];
}

// ---------------------------------------------------------------------------
// Input GEMM: Z[t][col][b] = sum_k A[t*64+b][k]*Wih[col][k] + bias[col]
// ---------------------------------------------------------------------------
template <int K>
__global__ __launch_bounds__(256, 4) void gemm_kernel(
    const unsigned short* __restrict__ A,    // [C*64][K] bf16
    const unsigned short* __restrict__ Bf,   // [512][K]
    const unsigned short* __restrict__ Bb,
    const unsigned short* __restrict__ biasf,  // [512]
    const unsigned short* __restrict__ biasb,
    float* __restrict__ Z)                   // [C][1024][64]
{
  constexpr int RS = K + 8;
  __shared__ __align__(16) unsigned short As[64 * RS];
  const int t = blockIdx.x, ns = blockIdx.y;
  const int tid = threadIdx.x, w = tid >> 6, lane = tid & 63;
  const int q = lane >> 4, cc = lane & 15;
  const unsigned short* Arow = A + (size_t)t * 64 * K;
  constexpr int K8 = K / 8;
  for (int ci = tid; ci < 64 * K8; ci += 256) {
    int r_ = ci / K8, c8 = ci % K8;
    *(short8*)&As[r_ * RS + c8 * 8] = *(const short8*)&Arow[r_ * K + c8 * 8];
  }
  __syncthreads();
  const int colbase = ns * 256 + w * 64;
  const unsigned short* Bp    = (colbase < 512) ? Bf : Bb;
  const unsigned short* biasp = (colbase < 512) ? biasf : biasb;
  const int cb = (colbase < 512) ? colbase : colbase - 512;
  floatx4 acc[4][4];
#pragma unroll
  for (int m = 0; m < 4; ++m)
#pragma unroll
    for (int n = 0; n < 4; ++n)
#pragma unroll
      for (int r = 0; r < 4; ++r) acc[m][n][r] = 0.f;
#pragma unroll
  for (int ks = 0; ks < K / 32; ++ks) {
    short8 af[4], bfr[4];
#pragma unroll
    for (int m = 0; m < 4; ++m)
      af[m] = *(const short8*)&As[(m * 16 + cc) * RS + ks * 32 + q * 8];
#pragma unroll
    for (int n = 0; n < 4; ++n)
      bfr[n] = *(const short8*)&Bp[(size_t)(cb + n * 16 + cc) * K + ks * 32 + q * 8];
#pragma unroll
    for (int m = 0; m < 4; ++m)
#pragma unroll
      for (int n = 0; n < 4; ++n)
        acc[m][n] = mfma16(af[m], bfr[n], acc[m][n]);
  }
#pragma unroll
  for (int n = 0; n < 4; ++n) {
    const int col = colbase + n * 16 + cc;
    const float bv = bf2f(biasp[cb + n * 16 + cc]);
#pragma unroll
    for (int m = 0; m < 4; ++m) {
      floatx4 v = acc[m][n];
      v += bv;
      *(floatx4*)&Z[(size_t)(t * 1024 + col) * 64 + m * 16 + q * 4] = v;
    }
  }
}

// ---------------------------------------------------------------------------
// FC head: one wave per (t,b). Output dtype via flag (1 = f32, 0 = bf16).
// ---------------------------------------------------------------------------
__global__ __launch_bounds__(256) void fc_kernel(
    const unsigned short* __restrict__ ys,   // [n][256] bf16
    const unsigned short* __restrict__ fcw,  // [256]
    const unsigned short* __restrict__ fcb,  // [1]
    void* __restrict__ out, size_t out_off, int n,
    const int* __restrict__ flag)
{
  const int gw = (int)((blockIdx.x * 256 + threadIdx.x) >> 6);
  const int lane = threadIdx.x & 63;
  if (gw >= n) return;
  const unsigned short* rp = ys + (size_t)gw * 256 + lane * 4;
  float s = 0.f;
#pragma unroll
  for (int i = 0; i < 4; ++i) s += bf2f(rp[i]) * bf2f(fcw[lane * 4 + i]);
#pragma unroll
  for (int m = 32; m >= 1; m >>= 1) s += __shfl_xor(s, m, 64);
  if (lane == 0) {
    const float v = fsig(s + bf2f(fcb[0]));
    if (*flag) ((float*)out)[out_off + gw] = v;
    else       ((unsigned short*)out)[out_off + gw] = f2bf(v);
  }
}

extern "C" void kernel_launch(void* const* d_in, const int* in_sizes, int n_in,
                              void* d_out, int out_size, void* d_ws, size_t ws_size,
                              hipStream_t stream)
{
  (void)in_sizes; (void)n_in; (void)out_size;
  const int S = 4096;

  int* flag = (int*)d_ws;
  unsigned short* wbuf = (unsigned short*)((char*)d_ws + 256);
  static const int woff[14] = {0,      49152,  114688, 115200, 164352, 229888,
                               230400, 361472, 427008, 427520, 558592, 624128,
                               624640, 624896};
  static const int wlen[14] = {49152, 65536, 512, 49152, 65536, 512,
                               131072, 65536, 512, 131072, 65536, 512,
                               256, 1};
  const size_t wbuf_end = 256 + 1250304;  // bytes

  int C = 1;
  for (int cand = 1024; cand >= 1; cand >>= 1) {
    size_t need = (size_t)cand * 602112 + wbuf_end + 196608;
    if (need <= ws_size) { C = cand; break; }
  }
  unsigned short* xbuf = (unsigned short*)((char*)d_ws + wbuf_end);
  float* Z0 = (float*)((char*)xbuf + (size_t)C * 12288);
  float* Z1 = Z0 + (size_t)C * 65536;
  unsigned short* ys0 = (unsigned short*)(Z1 + (size_t)C * 65536);
  unsigned short* ys1 = ys0 + (size_t)C * 16384;
  float* c0 = (float*)(ys1 + (size_t)C * 16384);
  float* c1 = c0 + 16384;
  unsigned short* h0 = (unsigned short*)(c1 + 16384);
  unsigned short* h1 = h0 + 16384;

  const unsigned short* wih0f = wbuf + woff[0];
  const unsigned short* whh0f = wbuf + woff[1];
  const unsigned short* b0f   = wbuf + woff[2];
  const unsigned short* wih0b = wbuf + woff[3];
  const unsigned short* whh0b = wbuf + woff[4];
  const unsigned short* b0b   = wbuf + woff[5];
  const unsigned short* wih1f = wbuf + woff[6];
  const unsigned short* whh1f = wbuf + woff[7];
  const unsigned short* b1f   = wbuf + woff[8];
  const unsigned short* wih1b = wbuf + woff[9];
  const unsigned short* whh1b = wbuf + woff[10];
  const unsigned short* b1b   = wbuf + woff[11];
  const unsigned short* fcw   = wbuf + woff[12];
  const unsigned short* fcb   = wbuf + woff[13];

  detect_kernel<<<1, 256, 0, stream>>>((const unsigned short*)d_in[1], 49152, flag);
  for (int i = 0; i < 14; ++i) {
    const int n = wlen[i];
    convert_kernel<<<(n + 1023) / 1024, 256, 0, stream>>>(
        d_in[1 + i], 0, wbuf + woff[i], n, flag);
  }

  const int nc = S / C;
  const int nx = C * 6144;

  // prologue: chunk 0, layer 0
  convert_kernel<<<(nx + 1023) / 1024, 256, 0, stream>>>(d_in[0], 0, xbuf, nx, flag);
  gemm_kernel<96><<<dim3(C, 4), 256, 0, stream>>>(xbuf, wih0f, wih0b, b0f, b0b, Z0);
  rec_kernel<<<8, 512, 0, stream>>>(Z0, whh0f, whh0b, ys0, c0, h0, 1,
                                    Z0, whh0f, whh0b, ys0, c0, h0, 1, C);
  // pipelined middle: layer0 chunk c fused with layer1 chunk c-1
  for (int c = 1; c < nc; ++c) {
    convert_kernel<<<(nx + 1023) / 1024, 256, 0, stream>>>(
        d_in[0], (size_t)c * nx, xbuf, nx, flag);
    gemm_kernel<96><<<dim3(C, 4), 256, 0, stream>>>(xbuf, wih0f, wih0b, b0f, b0b, Z0);
    gemm_kernel<256><<<dim3(C, 4), 256, 0, stream>>>(ys0, wih1f, wih1b, b1f, b1b, Z1);
    rec_kernel<<<16, 512, 0, stream>>>(Z0, whh0f, whh0b, ys0, c0, h0, 0,
                                       Z1, whh1f, whh1b, ys1, c1, h1, (c == 1) ? 1 : 0, C);
    fc_kernel<<<C * 16, 256, 0, stream>>>(ys1, fcw, fcb, d_out,
                                          (size_t)(c - 1) * C * 64, C * 64, flag);
  }
  // epilogue: layer1 chunk nc-1
  gemm_kernel<256><<<dim3(C, 4), 256, 0, stream>>>(ys0, wih1f, wih1b, b1f, b1b, Z1);
  rec_kernel<<<8, 512, 0, stream>>>(Z1, whh1f, whh1b, ys1, c1, h1, (nc == 1) ? 1 : 0,
                                    Z1, whh1f, whh1b, ys1, c1, h1, (nc == 1) ? 1 : 0, C);
  fc_kernel<<<C * 16, 256, 0, stream>>>(ys1, fcw, fcb, d_out,
                                        (size_t)(nc - 1) * C * 64, C * 64, flag);
}

// Round 5
// 8399.385 us; speedup vs baseline: 5.9220x; 1.2166x over previous
//
#include <hip/hip_runtime.h>
#include <stdint.h>

typedef short short8 __attribute__((ext_vector_type(8)));
typedef short short4v __attribute__((ext_vector_type(4)));
typedef float floatx4 __attribute__((ext_vector_type(4)));

#define LOG2E 1.44269504088896340736f

__device__ __forceinline__ float bf2f(unsigned short u) {
  unsigned v = ((unsigned)u) << 16;
  return __builtin_bit_cast(float, v);
}
__device__ __forceinline__ unsigned short f2bf(float f) {
  unsigned v = __builtin_bit_cast(unsigned, f);
  v += 0x7FFFu + ((v >> 16) & 1u);   // RNE
  return (unsigned short)(v >> 16);
}
__device__ __forceinline__ float fast_exp2(float x) {
#if __has_builtin(__builtin_amdgcn_exp2f)
  return __builtin_amdgcn_exp2f(x);
#else
  return exp2f(x);
#endif
}
__device__ __forceinline__ float fast_rcp(float x) {
#if __has_builtin(__builtin_amdgcn_rcpf)
  return __builtin_amdgcn_rcpf(x);
#else
  return 1.0f / x;
#endif
}
__device__ __forceinline__ float fsig(float x) {
  return fast_rcp(1.0f + fast_exp2(-LOG2E * x));
}
__device__ __forceinline__ float ftanh(float x) {
  float e = fast_exp2(2.0f * LOG2E * x);
  return 1.0f - 2.0f * fast_rcp(e + 1.0f);
}
__device__ __forceinline__ floatx4 mfma16(short8 a, short8 b, floatx4 c) {
  return __builtin_amdgcn_mfma_f32_16x16x32_bf16(a, b, c, 0, 0, 0);
}

// ---------------------------------------------------------------------------
// Dtype detection: if the buffer is float32, even-indexed u16 halves are float
// mantissa bits -> ~6% have bf16-exponent >= 0xF0. If bf16 (0.05-scaled
// weights), exponent <= 125 always -> 0 hits. flag: 1 = f32, 0 = bf16.
// ---------------------------------------------------------------------------
__global__ __launch_bounds__(256) void detect_kernel(
    const unsigned short* __restrict__ w, int n_u16, int* __restrict__ flag)
{
  __shared__ int cnt;
  if (threadIdx.x == 0) cnt = 0;
  __syncthreads();
  int local = 0;
  for (int i = threadIdx.x * 2; i < n_u16; i += 512) {  // even indices only
    unsigned e = (w[i] >> 7) & 0xFF;
    if (e >= 0xF0) local++;
  }
  atomicAdd(&cnt, local);
  __syncthreads();
  if (threadIdx.x == 0) *flag = (cnt > 64) ? 1 : 0;
}

__global__ __launch_bounds__(256) void convert_kernel(
    const void* __restrict__ src, size_t src_off,
    unsigned short* __restrict__ dst, int n, const int* __restrict__ flag)
{
  const int base = (int)(blockIdx.x * 256 + threadIdx.x) * 4;
  if (base >= n) return;
  if (*flag) {
    const float* s = (const float*)src + src_off;
#pragma unroll
    for (int j = 0; j < 4; ++j)
      if (base + j < n) dst[base + j] = f2bf(s[base + j]);
  } else {
    const unsigned short* s = (const unsigned short*)src + src_off;
#pragma unroll
    for (int j = 0; j < 4; ++j)
      if (base + j < n) dst[base + j] = s[base + j];
  }
}

// ---------------------------------------------------------------------------
// Fused recurrent kernel. Two layer contexts (a = layer L0 chunk c,
// b = layer L1 chunk c-1); blocks 0..7 -> ctx a, 8..15 -> ctx b.
// Within a context: block = dir*4 + batch-group (16 batch rows each).
// Z(t+1) is prefetched into registers during step t: the load is independent
// of the recurrence, so its ~900-cycle HBM latency overlaps step t's
// MFMA+pointwise instead of sitting on the serial critical path.
// ---------------------------------------------------------------------------
__global__ __launch_bounds__(512, 2) void rec_kernel(
    const float* __restrict__ Za, const unsigned short* __restrict__ whhfa,
    const unsigned short* __restrict__ whhba,
    unsigned short* __restrict__ ysa, float* __restrict__ ca,
    unsigned short* __restrict__ ha, int inita,
    const float* __restrict__ Zb, const unsigned short* __restrict__ whhfb,
    const unsigned short* __restrict__ whhbb,
    unsigned short* __restrict__ ysb, float* __restrict__ cb,
    unsigned short* __restrict__ hb, int initb,
    int steps)
{
  __shared__ __align__(16) unsigned short hbuf[2][16][136];
  const int blk = blockIdx.x;
  const float* Z;
  const unsigned short* whhF;
  const unsigned short* whhB;
  unsigned short* ys;
  float* cst;
  unsigned short* hst;
  int init;
  if (blk < 8) {
    Z = Za; whhF = whhfa; whhB = whhba; ys = ysa; cst = ca; hst = ha; init = inita;
  } else {
    Z = Zb; whhF = whhfb; whhB = whhbb; ys = ysb; cst = cb; hst = hb; init = initb;
  }
  const int d = (blk >> 2) & 1, bg = blk & 3;
  const unsigned short* whh = d ? whhB : whhF;

  const int tid = threadIdx.x;
  const int w = tid >> 6, lane = tid & 63, q = lane >> 4, cc = lane & 15;
  const int u = w * 16 + cc;

  // Whh as MFMA B-fragments, register-resident (64 VGPRs).
  short8 bfrag[4][4];
#pragma unroll
  for (int g = 0; g < 4; ++g)
#pragma unroll
    for (int k = 0; k < 4; ++k)
      bfrag[g][k] = *(const short8*)(whh + (size_t)(g * 128 + u) * 128 + k * 32 + q * 8);

  float creg[4];
  const int row = tid >> 5;          // 0..15
  const int col4 = (tid & 31) * 4;   // 0..124
  if (init) {
#pragma unroll
    for (int r = 0; r < 4; ++r) creg[r] = 0.f;
    short4v zz = {0, 0, 0, 0};
    *(short4v*)&hbuf[0][row][col4] = zz;
  } else {
#pragma unroll
    for (int r = 0; r < 4; ++r)
      creg[r] = cst[(size_t)(d * 64 + bg * 16 + q * 4 + r) * 128 + u];
    *(short4v*)&hbuf[0][row][col4] =
        *(const short4v*)(hst + (size_t)(d * 64 + bg * 16 + row) * 128 + col4);
  }
  __syncthreads();

  const int zlane = (d * 512 + u) * 64 + bg * 16 + q * 4;
  // prime the software pipeline: Z(0)
  floatx4 znext[4];
#pragma unroll
  for (int g = 0; g < 4; ++g)
    znext[g] = *(const floatx4*)(Z + zlane + g * 8192);

  for (int t = 0; t < steps; ++t) {
    const int cur = t & 1, nxt = cur ^ 1;
    // consume prefetched Z(t)
    floatx4 acc[4];
#pragma unroll
    for (int g = 0; g < 4; ++g) acc[g] = znext[g];
    // issue prefetch of Z(t+1) (clamped) before the MFMA block
    const int tn = (t + 1 < steps) ? t + 1 : t;
    const float* ztn = Z + (size_t)tn * 65536 + zlane;
#pragma unroll
    for (int g = 0; g < 4; ++g)
      znext[g] = *(const floatx4*)(ztn + g * 8192);

    short8 af[4];
#pragma unroll
    for (int k = 0; k < 4; ++k)
      af[k] = *(const short8*)&hbuf[cur][cc][k * 32 + q * 8];
#pragma unroll
    for (int g = 0; g < 4; ++g)
#pragma unroll
      for (int k = 0; k < 4; ++k)
        acc[g] = mfma16(af[k], bfrag[g][k], acc[g]);
    // pointwise: lane owns (batch bg*16 + q*4+r, unit u), gates local
#pragma unroll
    for (int r = 0; r < 4; ++r) {
      float zi = acc[0][r], zf = acc[1][r], zg = acc[2][r], zo = acc[3][r];
      float cn = fsig(zf) * creg[r] + fsig(zi) * ftanh(zg);
      creg[r] = cn;
      hbuf[nxt][q * 4 + r][u] = f2bf(fsig(zo) * ftanh(cn));
    }
    __syncthreads();
    unsigned short* yd = ys + (size_t)(t * 64 + bg * 16 + row) * 256 + d * 128 + col4;
    *(short4v*)yd = *(const short4v*)&hbuf[nxt][row][col4];
  }
#pragma unroll
  for (int r = 0; r < 4; ++r)
    cst[(size_t)(d * 64 + bg * 16 + q * 4 + r) * 128 + u] = creg[r];
  const int fin = steps & 1;
  *(short4v*)(hst + (size_t)(d * 64 + bg * 16 + row) * 128 + col4) =
      *(const short4v*)&hbuf[fin][row][col4];
}

// ---------------------------------------------------------------------------
// Input GEMM: Z[t][col][b] = sum_k A[t*64+b][k]*Wih[col][k] + bias[col]
// ---------------------------------------------------------------------------
template <int K>
__global__ __launch_bounds__(256, 4) void gemm_kernel(
    const unsigned short* __restrict__ A,    // [C*64][K] bf16
    const unsigned short* __restrict__ Bf,   // [512][K]
    const unsigned short* __restrict__ Bb,
    const unsigned short* __restrict__ biasf,  // [512]
    const unsigned short* __restrict__ biasb,
    float* __restrict__ Z)                   // [C][1024][64]
{
  constexpr int RS = K + 8;
  __shared__ __align__(16) unsigned short As[64 * RS];
  const int t = blockIdx.x, ns = blockIdx.y;
  const int tid = threadIdx.x, w = tid >> 6, lane = tid & 63;
  const int q = lane >> 4, cc = lane & 15;
  const unsigned short* Arow = A + (size_t)t * 64 * K;
  constexpr int K8 = K / 8;
  for (int ci = tid; ci < 64 * K8; ci += 256) {
    int r_ = ci / K8, c8 = ci % K8;
    *(short8*)&As[r_ * RS + c8 * 8] = *(const short8*)&Arow[r_ * K + c8 * 8];
  }
  __syncthreads();
  const int colbase = ns * 256 + w * 64;
  const unsigned short* Bp    = (colbase < 512) ? Bf : Bb;
  const unsigned short* biasp = (colbase < 512) ? biasf : biasb;
  const int cb = (colbase < 512) ? colbase : colbase - 512;
  floatx4 acc[4][4];
#pragma unroll
  for (int m = 0; m < 4; ++m)
#pragma unroll
    for (int n = 0; n < 4; ++n)
#pragma unroll
      for (int r = 0; r < 4; ++r) acc[m][n][r] = 0.f;
#pragma unroll
  for (int ks = 0; ks < K / 32; ++ks) {
    short8 af[4], bfr[4];
#pragma unroll
    for (int m = 0; m < 4; ++m)
      af[m] = *(const short8*)&As[(m * 16 + cc) * RS + ks * 32 + q * 8];
#pragma unroll
    for (int n = 0; n < 4; ++n)
      bfr[n] = *(const short8*)&Bp[(size_t)(cb + n * 16 + cc) * K + ks * 32 + q * 8];
#pragma unroll
    for (int m = 0; m < 4; ++m)
#pragma unroll
      for (int n = 0; n < 4; ++n)
        acc[m][n] = mfma16(af[m], bfr[n], acc[m][n]);
  }
#pragma unroll
  for (int n = 0; n < 4; ++n) {
    const int col = colbase + n * 16 + cc;
    const float bv = bf2f(biasp[cb + n * 16 + cc]);
#pragma unroll
    for (int m = 0; m < 4; ++m) {
      floatx4 v = acc[m][n];
      v += bv;
      *(floatx4*)&Z[(size_t)(t * 1024 + col) * 64 + m * 16 + q * 4] = v;
    }
  }
}

// ---------------------------------------------------------------------------
// FC head: one wave per (t,b). Output dtype via flag (1 = f32, 0 = bf16).
// ---------------------------------------------------------------------------
__global__ __launch_bounds__(256) void fc_kernel(
    const unsigned short* __restrict__ ys,   // [n][256] bf16
    const unsigned short* __restrict__ fcw,  // [256]
    const unsigned short* __restrict__ fcb,  // [1]
    void* __restrict__ out, size_t out_off, int n,
    const int* __restrict__ flag)
{
  const int gw = (int)((blockIdx.x * 256 + threadIdx.x) >> 6);
  const int lane = threadIdx.x & 63;
  if (gw >= n) return;
  const unsigned short* rp = ys + (size_t)gw * 256 + lane * 4;
  float s = 0.f;
#pragma unroll
  for (int i = 0; i < 4; ++i) s += bf2f(rp[i]) * bf2f(fcw[lane * 4 + i]);
#pragma unroll
  for (int m = 32; m >= 1; m >>= 1) s += __shfl_xor(s, m, 64);
  if (lane == 0) {
    const float v = fsig(s + bf2f(fcb[0]));
    if (*flag) ((float*)out)[out_off + gw] = v;
    else       ((unsigned short*)out)[out_off + gw] = f2bf(v);
  }
}

extern "C" void kernel_launch(void* const* d_in, const int* in_sizes, int n_in,
                              void* d_out, int out_size, void* d_ws, size_t ws_size,
                              hipStream_t stream)
{
  (void)in_sizes; (void)n_in; (void)out_size;
  const int S = 4096;

  int* flag = (int*)d_ws;
  unsigned short* wbuf = (unsigned short*)((char*)d_ws + 256);
  static const int woff[14] = {0,      49152,  114688, 115200, 164352, 229888,
                               230400, 361472, 427008, 427520, 558592, 624128,
                               624640, 624896};
  static const int wlen[14] = {49152, 65536, 512, 49152, 65536, 512,
                               131072, 65536, 512, 131072, 65536, 512,
                               256, 1};
  const size_t wbuf_end = 256 + 1250304;  // bytes

  int C = 1;
  for (int cand = 1024; cand >= 1; cand >>= 1) {
    size_t need = (size_t)cand * 602112 + wbuf_end + 196608;
    if (need <= ws_size) { C = cand; break; }
  }
  unsigned short* xbuf = (unsigned short*)((char*)d_ws + wbuf_end);
  float* Z0 = (float*)((char*)xbuf + (size_t)C * 12288);
  float* Z1 = Z0 + (size_t)C * 65536;
  unsigned short* ys0 = (unsigned short*)(Z1 + (size_t)C * 65536);
  unsigned short* ys1 = ys0 + (size_t)C * 16384;
  float* c0 = (float*)(ys1 + (size_t)C * 16384);
  float* c1 = c0 + 16384;
  unsigned short* h0 = (unsigned short*)(c1 + 16384);
  unsigned short* h1 = h0 + 16384;

  const unsigned short* wih0f = wbuf + woff[0];
  const unsigned short* whh0f = wbuf + woff[1];
  const unsigned short* b0f   = wbuf + woff[2];
  const unsigned short* wih0b = wbuf + woff[3];
  const unsigned short* whh0b = wbuf + woff[4];
  const unsigned short* b0b   = wbuf + woff[5];
  const unsigned short* wih1f = wbuf + woff[6];
  const unsigned short* whh1f = wbuf + woff[7];
  const unsigned short* b1f   = wbuf + woff[8];
  const unsigned short* wih1b = wbuf + woff[9];
  const unsigned short* whh1b = wbuf + woff[10];
  const unsigned short* b1b   = wbuf + woff[11];
  const unsigned short* fcw   = wbuf + woff[12];
  const unsigned short* fcb   = wbuf + woff[13];

  detect_kernel<<<1, 256, 0, stream>>>((const unsigned short*)d_in[1], 49152, flag);
  for (int i = 0; i < 14; ++i) {
    const int n = wlen[i];
    convert_kernel<<<(n + 1023) / 1024, 256, 0, stream>>>(
        d_in[1 + i], 0, wbuf + woff[i], n, flag);
  }

  const int nc = S / C;
  const int nx = C * 6144;

  // prologue: chunk 0, layer 0
  convert_kernel<<<(nx + 1023) / 1024, 256, 0, stream>>>(d_in[0], 0, xbuf, nx, flag);
  gemm_kernel<96><<<dim3(C, 4), 256, 0, stream>>>(xbuf, wih0f, wih0b, b0f, b0b, Z0);
  rec_kernel<<<8, 512, 0, stream>>>(Z0, whh0f, whh0b, ys0, c0, h0, 1,
                                    Z0, whh0f, whh0b, ys0, c0, h0, 1, C);
  // pipelined middle: layer0 chunk c fused with layer1 chunk c-1
  for (int c = 1; c < nc; ++c) {
    convert_kernel<<<(nx + 1023) / 1024, 256, 0, stream>>>(
        d_in[0], (size_t)c * nx, xbuf, nx, flag);
    gemm_kernel<96><<<dim3(C, 4), 256, 0, stream>>>(xbuf, wih0f, wih0b, b0f, b0b, Z0);
    gemm_kernel<256><<<dim3(C, 4), 256, 0, stream>>>(ys0, wih1f, wih1b, b1f, b1b, Z1);
    rec_kernel<<<16, 512, 0, stream>>>(Z0, whh0f, whh0b, ys0, c0, h0, 0,
                                       Z1, whh1f, whh1b, ys1, c1, h1, (c == 1) ? 1 : 0, C);
    fc_kernel<<<C * 16, 256, 0, stream>>>(ys1, fcw, fcb, d_out,
                                          (size_t)(c - 1) * C * 64, C * 64, flag);
  }
  // epilogue: layer1 chunk nc-1
  gemm_kernel<256><<<dim3(C, 4), 256, 0, stream>>>(ys0, wih1f, wih1b, b1f, b1b, Z1);
  rec_kernel<<<8, 512, 0, stream>>>(Z1, whh1f, whh1b, ys1, c1, h1, (nc == 1) ? 1 : 0,
                                    Z1, whh1f, whh1b, ys1, c1, h1, (nc == 1) ? 1 : 0, C);
  fc_kernel<<<C * 16, 256, 0, stream>>>(ys1, fcw, fcb, d_out,
                                        (size_t)(nc - 1) * C * 64, C * 64, flag);
}

// Round 6
// 8101.450 us; speedup vs baseline: 6.1398x; 1.0368x over previous
//
#include <hip/hip_runtime.h>
#include <stdint.h>

typedef short short8 __attribute__((ext_vector_type(8)));
typedef short short4v __attribute__((ext_vector_type(4)));
typedef float floatx4 __attribute__((ext_vector_type(4)));

#define LOG2E 1.44269504088896340736f

__device__ __forceinline__ float bf2f(unsigned short u) {
  unsigned v = ((unsigned)u) << 16;
  return __builtin_bit_cast(float, v);
}
__device__ __forceinline__ unsigned short f2bf(float f) {
  unsigned v = __builtin_bit_cast(unsigned, f);
  v += 0x7FFFu + ((v >> 16) & 1u);   // RNE
  return (unsigned short)(v >> 16);
}
__device__ __forceinline__ float fast_exp2(float x) {
#if __has_builtin(__builtin_amdgcn_exp2f)
  return __builtin_amdgcn_exp2f(x);
#else
  return exp2f(x);
#endif
}
__device__ __forceinline__ float fast_rcp(float x) {
#if __has_builtin(__builtin_amdgcn_rcpf)
  return __builtin_amdgcn_rcpf(x);
#else
  return 1.0f / x;
#endif
}
__device__ __forceinline__ float fsig(float x) {
  return fast_rcp(1.0f + fast_exp2(-LOG2E * x));
}
__device__ __forceinline__ float ftanh(float x) {
  float e = fast_exp2(2.0f * LOG2E * x);
  return 1.0f - 2.0f * fast_rcp(e + 1.0f);
}
__device__ __forceinline__ floatx4 mfma16(short8 a, short8 b, floatx4 c) {
  return __builtin_amdgcn_mfma_f32_16x16x32_bf16(a, b, c, 0, 0, 0);
}

// ---------------------------------------------------------------------------
// Dtype detection: if the buffer is float32, even-indexed u16 halves are float
// mantissa bits -> ~6% have bf16-exponent >= 0xF0. If bf16 (0.05-scaled
// weights), exponent <= 125 always -> 0 hits. flag: 1 = f32, 0 = bf16.
// ---------------------------------------------------------------------------
__global__ __launch_bounds__(256) void detect_kernel(
    const unsigned short* __restrict__ w, int n_u16, int* __restrict__ flag)
{
  __shared__ int cnt;
  if (threadIdx.x == 0) cnt = 0;
  __syncthreads();
  int local = 0;
  for (int i = threadIdx.x * 2; i < n_u16; i += 512) {  // even indices only
    unsigned e = (w[i] >> 7) & 0xFF;
    if (e >= 0xF0) local++;
  }
  atomicAdd(&cnt, local);
  __syncthreads();
  if (threadIdx.x == 0) *flag = (cnt > 64) ? 1 : 0;
}

__global__ __launch_bounds__(256) void convert_kernel(
    const void* __restrict__ src, size_t src_off,
    unsigned short* __restrict__ dst, int n, const int* __restrict__ flag)
{
  const int base = (int)(blockIdx.x * 256 + threadIdx.x) * 4;
  if (base >= n) return;
  if (*flag) {
    const float* s = (const float*)src + src_off;
#pragma unroll
    for (int j = 0; j < 4; ++j)
      if (base + j < n) dst[base + j] = f2bf(s[base + j]);
  } else {
    const unsigned short* s = (const unsigned short*)src + src_off;
#pragma unroll
    for (int j = 0; j < 4; ++j)
      if (base + j < n) dst[base + j] = s[base + j];
  }
}

// ---------------------------------------------------------------------------
// Fused recurrent kernel. Two layer contexts (a = layer L0 chunk c,
// b = layer L1 chunk c-1); blocks 0..7 -> ctx a, 8..15 -> ctx b.
// Within a context: block = dir*4 + batch-group (16 batch rows each).
// Z is bf16 [steps][1024][64] (col = dir*512 + gate*128 + unit, batch fastest).
// Z(t+1) is prefetched at the TOP of step t and pinned there with
// sched_barrier(0), so the vmcnt(0) drain at the step barrier finds the
// loads already complete (the whole body ~2500 cyc covers L3/HBM latency).
// ---------------------------------------------------------------------------
__global__ __launch_bounds__(512, 2) void rec_kernel(
    const unsigned short* __restrict__ Za, const unsigned short* __restrict__ whhfa,
    const unsigned short* __restrict__ whhba,
    unsigned short* __restrict__ ysa, float* __restrict__ ca,
    unsigned short* __restrict__ ha, int inita,
    const unsigned short* __restrict__ Zb, const unsigned short* __restrict__ whhfb,
    const unsigned short* __restrict__ whhbb,
    unsigned short* __restrict__ ysb, float* __restrict__ cb,
    unsigned short* __restrict__ hb, int initb,
    int steps)
{
  __shared__ __align__(16) unsigned short hbuf[2][16][136];
  const int blk = blockIdx.x;
  const unsigned short* Z;
  const unsigned short* whhF;
  const unsigned short* whhB;
  unsigned short* ys;
  float* cst;
  unsigned short* hst;
  int init;
  if (blk < 8) {
    Z = Za; whhF = whhfa; whhB = whhba; ys = ysa; cst = ca; hst = ha; init = inita;
  } else {
    Z = Zb; whhF = whhfb; whhB = whhbb; ys = ysb; cst = cb; hst = hb; init = initb;
  }
  const int d = (blk >> 2) & 1, bg = blk & 3;
  const unsigned short* whh = d ? whhB : whhF;

  const int tid = threadIdx.x;
  const int w = tid >> 6, lane = tid & 63, q = lane >> 4, cc = lane & 15;
  const int u = w * 16 + cc;

  // Whh as MFMA B-fragments, register-resident (64 regs, likely AGPR).
  short8 bfrag[4][4];
#pragma unroll
  for (int g = 0; g < 4; ++g)
#pragma unroll
    for (int k = 0; k < 4; ++k)
      bfrag[g][k] = *(const short8*)(whh + (size_t)(g * 128 + u) * 128 + k * 32 + q * 8);

  float creg[4];
  const int row = tid >> 5;          // 0..15
  const int col4 = (tid & 31) * 4;   // 0..124
  if (init) {
#pragma unroll
    for (int r = 0; r < 4; ++r) creg[r] = 0.f;
    short4v zz = {0, 0, 0, 0};
    *(short4v*)&hbuf[0][row][col4] = zz;
  } else {
#pragma unroll
    for (int r = 0; r < 4; ++r)
      creg[r] = cst[(size_t)(d * 64 + bg * 16 + q * 4 + r) * 128 + u];
    *(short4v*)&hbuf[0][row][col4] =
        *(const short4v*)(hst + (size_t)(d * 64 + bg * 16 + row) * 128 + col4);
  }
  __syncthreads();

  const int zlane = (d * 512 + u) * 64 + bg * 16 + q * 4;
  // prime: Z(0) in bf16
  short4v zcur[4];
#pragma unroll
  for (int g = 0; g < 4; ++g)
    zcur[g] = *(const short4v*)(Z + zlane + g * 8192);

  for (int t = 0; t < steps; ++t) {
    const int cur = t & 1, nxt = cur ^ 1;
    // issue prefetch of Z(t+1) FIRST, pinned by a scheduling barrier
    const int tn = (t + 1 < steps) ? t + 1 : t;
    const unsigned short* ztn = Z + (size_t)tn * 65536 + zlane;
    short4v zpf[4];
#pragma unroll
    for (int g = 0; g < 4; ++g)
      zpf[g] = *(const short4v*)(ztn + g * 8192);
    __builtin_amdgcn_sched_barrier(0);

    // convert current z (bf16 -> fp32) into C-layout accumulators
    floatx4 acc[4];
#pragma unroll
    for (int g = 0; g < 4; ++g)
#pragma unroll
      for (int r = 0; r < 4; ++r)
        acc[g][r] = bf2f((unsigned short)zcur[g][r]);

    short8 af[4];
#pragma unroll
    for (int k = 0; k < 4; ++k)
      af[k] = *(const short8*)&hbuf[cur][cc][k * 32 + q * 8];
#pragma unroll
    for (int g = 0; g < 4; ++g)
#pragma unroll
      for (int k = 0; k < 4; ++k)
        acc[g] = mfma16(af[k], bfrag[g][k], acc[g]);
    // pointwise: lane owns (batch bg*16 + q*4+r, unit u), gates local
#pragma unroll
    for (int r = 0; r < 4; ++r) {
      float zi = acc[0][r], zf = acc[1][r], zg = acc[2][r], zo = acc[3][r];
      float cn = fsig(zf) * creg[r] + fsig(zi) * ftanh(zg);
      creg[r] = cn;
      hbuf[nxt][q * 4 + r][u] = f2bf(fsig(zo) * ftanh(cn));
    }
    __syncthreads();
    unsigned short* yd = ys + (size_t)(t * 64 + bg * 16 + row) * 256 + d * 128 + col4;
    *(short4v*)yd = *(const short4v*)&hbuf[nxt][row][col4];
#pragma unroll
    for (int g = 0; g < 4; ++g) zcur[g] = zpf[g];
  }
#pragma unroll
  for (int r = 0; r < 4; ++r)
    cst[(size_t)(d * 64 + bg * 16 + q * 4 + r) * 128 + u] = creg[r];
  const int fin = steps & 1;
  *(short4v*)(hst + (size_t)(d * 64 + bg * 16 + row) * 128 + col4) =
      *(const short4v*)&hbuf[fin][row][col4];
}

// ---------------------------------------------------------------------------
// Input GEMM: Z[t][col][b] = sum_k A[t*64+b][k]*Wih[col][k] + bias[col]
// Z output is bf16 (halves traffic; keeps Z0+Z1 L3-resident at C=512).
// ---------------------------------------------------------------------------
template <int K>
__global__ __launch_bounds__(256, 4) void gemm_kernel(
    const unsigned short* __restrict__ A,    // [C*64][K] bf16
    const unsigned short* __restrict__ Bf,   // [512][K]
    const unsigned short* __restrict__ Bb,
    const unsigned short* __restrict__ biasf,  // [512]
    const unsigned short* __restrict__ biasb,
    unsigned short* __restrict__ Z)          // [C][1024][64] bf16
{
  constexpr int RS = K + 8;
  __shared__ __align__(16) unsigned short As[64 * RS];
  const int t = blockIdx.x, ns = blockIdx.y;
  const int tid = threadIdx.x, w = tid >> 6, lane = tid & 63;
  const int q = lane >> 4, cc = lane & 15;
  const unsigned short* Arow = A + (size_t)t * 64 * K;
  constexpr int K8 = K / 8;
  for (int ci = tid; ci < 64 * K8; ci += 256) {
    int r_ = ci / K8, c8 = ci % K8;
    *(short8*)&As[r_ * RS + c8 * 8] = *(const short8*)&Arow[r_ * K + c8 * 8];
  }
  __syncthreads();
  const int colbase = ns * 256 + w * 64;
  const unsigned short* Bp    = (colbase < 512) ? Bf : Bb;
  const unsigned short* biasp = (colbase < 512) ? biasf : biasb;
  const int cb = (colbase < 512) ? colbase : colbase - 512;
  floatx4 acc[4][4];
#pragma unroll
  for (int m = 0; m < 4; ++m)
#pragma unroll
    for (int n = 0; n < 4; ++n)
#pragma unroll
      for (int r = 0; r < 4; ++r) acc[m][n][r] = 0.f;
#pragma unroll
  for (int ks = 0; ks < K / 32; ++ks) {
    short8 af[4], bfr[4];
#pragma unroll
    for (int m = 0; m < 4; ++m)
      af[m] = *(const short8*)&As[(m * 16 + cc) * RS + ks * 32 + q * 8];
#pragma unroll
    for (int n = 0; n < 4; ++n)
      bfr[n] = *(const short8*)&Bp[(size_t)(cb + n * 16 + cc) * K + ks * 32 + q * 8];
#pragma unroll
    for (int m = 0; m < 4; ++m)
#pragma unroll
      for (int n = 0; n < 4; ++n)
        acc[m][n] = mfma16(af[m], bfr[n], acc[m][n]);
  }
#pragma unroll
  for (int n = 0; n < 4; ++n) {
    const int col = colbase + n * 16 + cc;
    const float bv = bf2f(biasp[cb + n * 16 + cc]);
#pragma unroll
    for (int m = 0; m < 4; ++m) {
      short4v zv;
#pragma unroll
      for (int r = 0; r < 4; ++r)
        zv[r] = (short)f2bf(acc[m][n][r] + bv);
      *(short4v*)&Z[(size_t)(t * 1024 + col) * 64 + m * 16 + q * 4] = zv;
    }
  }
}

// ---------------------------------------------------------------------------
// FC head: one wave per (t,b). Output dtype via flag (1 = f32, 0 = bf16).
// ---------------------------------------------------------------------------
__global__ __launch_bounds__(256) void fc_kernel(
    const unsigned short* __restrict__ ys,   // [n][256] bf16
    const unsigned short* __restrict__ fcw,  // [256]
    const unsigned short* __restrict__ fcb,  // [1]
    void* __restrict__ out, size_t out_off, int n,
    const int* __restrict__ flag)
{
  const int gw = (int)((blockIdx.x * 256 + threadIdx.x) >> 6);
  const int lane = threadIdx.x & 63;
  if (gw >= n) return;
  const unsigned short* rp = ys + (size_t)gw * 256 + lane * 4;
  float s = 0.f;
#pragma unroll
  for (int i = 0; i < 4; ++i) s += bf2f(rp[i]) * bf2f(fcw[lane * 4 + i]);
#pragma unroll
  for (int m = 32; m >= 1; m >>= 1) s += __shfl_xor(s, m, 64);
  if (lane == 0) {
    const float v = fsig(s + bf2f(fcb[0]));
    if (*flag) ((float*)out)[out_off + gw] = v;
    else       ((unsigned short*)out)[out_off + gw] = f2bf(v);
  }
}

extern "C" void kernel_launch(void* const* d_in, const int* in_sizes, int n_in,
                              void* d_out, int out_size, void* d_ws, size_t ws_size,
                              hipStream_t stream)
{
  (void)in_sizes; (void)n_in; (void)out_size;
  const int S = 4096;

  int* flag = (int*)d_ws;
  unsigned short* wbuf = (unsigned short*)((char*)d_ws + 256);
  static const int woff[14] = {0,      49152,  114688, 115200, 164352, 229888,
                               230400, 361472, 427008, 427520, 558592, 624128,
                               624640, 624896};
  static const int wlen[14] = {49152, 65536, 512, 49152, 65536, 512,
                               131072, 65536, 512, 131072, 65536, 512,
                               256, 1};
  const size_t wbuf_end = 256 + 1250304;  // bytes

  // Per-step bytes: xbuf 12288 + Z0 131072 + Z1 131072 + ys0 32768 +
  // ys1 32768 = 339968. Fixed: wbuf_end + state 196608.
  // C capped at 512 so Z0+Z1 (134 MB bf16) stays L3-resident.
  int C = 1;
  for (int cand = 512; cand >= 1; cand >>= 1) {
    size_t need = (size_t)cand * 339968 + wbuf_end + 196608;
    if (need <= ws_size) { C = cand; break; }
  }
  unsigned short* xbuf = (unsigned short*)((char*)d_ws + wbuf_end);
  unsigned short* Z0 = xbuf + (size_t)C * 6144;      // C*65536 u16
  unsigned short* Z1 = Z0 + (size_t)C * 65536;       // C*65536 u16
  unsigned short* ys0 = Z1 + (size_t)C * 65536;      // C*16384 u16
  unsigned short* ys1 = ys0 + (size_t)C * 16384;
  float* c0 = (float*)(ys1 + (size_t)C * 16384);
  float* c1 = c0 + 16384;
  unsigned short* h0 = (unsigned short*)(c1 + 16384);
  unsigned short* h1 = h0 + 16384;

  const unsigned short* wih0f = wbuf + woff[0];
  const unsigned short* whh0f = wbuf + woff[1];
  const unsigned short* b0f   = wbuf + woff[2];
  const unsigned short* wih0b = wbuf + woff[3];
  const unsigned short* whh0b = wbuf + woff[4];
  const unsigned short* b0b   = wbuf + woff[5];
  const unsigned short* wih1f = wbuf + woff[6];
  const unsigned short* whh1f = wbuf + woff[7];
  const unsigned short* b1f   = wbuf + woff[8];
  const unsigned short* wih1b = wbuf + woff[9];
  const unsigned short* whh1b = wbuf + woff[10];
  const unsigned short* b1b   = wbuf + woff[11];
  const unsigned short* fcw   = wbuf + woff[12];
  const unsigned short* fcb   = wbuf + woff[13];

  detect_kernel<<<1, 256, 0, stream>>>((const unsigned short*)d_in[1], 49152, flag);
  for (int i = 0; i < 14; ++i) {
    const int n = wlen[i];
    convert_kernel<<<(n + 1023) / 1024, 256, 0, stream>>>(
        d_in[1 + i], 0, wbuf + woff[i], n, flag);
  }

  const int nc = S / C;
  const int nx = C * 6144;

  // prologue: chunk 0, layer 0
  convert_kernel<<<(nx + 1023) / 1024, 256, 0, stream>>>(d_in[0], 0, xbuf, nx, flag);
  gemm_kernel<96><<<dim3(C, 4), 256, 0, stream>>>(xbuf, wih0f, wih0b, b0f, b0b, Z0);
  rec_kernel<<<8, 512, 0, stream>>>(Z0, whh0f, whh0b, ys0, c0, h0, 1,
                                    Z0, whh0f, whh0b, ys0, c0, h0, 1, C);
  // pipelined middle: layer0 chunk c fused with layer1 chunk c-1
  for (int c = 1; c < nc; ++c) {
    convert_kernel<<<(nx + 1023) / 1024, 256, 0, stream>>>(
        d_in[0], (size_t)c * nx, xbuf, nx, flag);
    gemm_kernel<96><<<dim3(C, 4), 256, 0, stream>>>(xbuf, wih0f, wih0b, b0f, b0b, Z0);
    gemm_kernel<256><<<dim3(C, 4), 256, 0, stream>>>(ys0, wih1f, wih1b, b1f, b1b, Z1);
    rec_kernel<<<16, 512, 0, stream>>>(Z0, whh0f, whh0b, ys0, c0, h0, 0,
                                       Z1, whh1f, whh1b, ys1, c1, h1, (c == 1) ? 1 : 0, C);
    fc_kernel<<<C * 16, 256, 0, stream>>>(ys1, fcw, fcb, d_out,
                                          (size_t)(c - 1) * C * 64, C * 64, flag);
  }
  // epilogue: layer1 chunk nc-1
  gemm_kernel<256><<<dim3(C, 4), 256, 0, stream>>>(ys0, wih1f, wih1b, b1f, b1b, Z1);
  rec_kernel<<<8, 512, 0, stream>>>(Z1, whh1f, whh1b, ys1, c1, h1, (nc == 1) ? 1 : 0,
                                    Z1, whh1f, whh1b, ys1, c1, h1, (nc == 1) ? 1 : 0, C);
  fc_kernel<<<C * 16, 256, 0, stream>>>(ys1, fcw, fcb, d_out,
                                        (size_t)(nc - 1) * C * 64, C * 64, flag);
}